// Round 2
// baseline (960.054 us; speedup 1.0000x reference)
//
#include <hip/hip_runtime.h>
#include <hip/hip_bf16.h>

#define N_NODES 8192

typedef __attribute__((ext_vector_type(8))) short short8;
typedef __attribute__((ext_vector_type(8))) unsigned short ushort8;
typedef __attribute__((ext_vector_type(4))) unsigned short ushort4v;
typedef __attribute__((ext_vector_type(4))) float floatx4;

__device__ inline unsigned short f2bf(float f) {
  unsigned int u = __float_as_uint(f);
  u = (u + 0x7FFFu + ((u >> 16) & 1u)) >> 16;  // RNE, no NaNs in this data
  return (unsigned short)u;
}

__device__ inline float waveSum(float s) {
#pragma unroll
  for (int off = 32; off >= 1; off >>= 1) s += __shfl_xor(s, off, 64);
  return s;
}

__device__ inline void acc4(float4& a, const float4 b) {
  a.x += b.x; a.y += b.y; a.z += b.z; a.w += b.w;
}
__device__ inline float hsum4(const float4 v) { return v.x + v.y + v.z + v.w; }

__device__ inline short8 cvt8(const float4 lo, const float4 hi) {
  short8 r;
  r[0] = (short)f2bf(lo.x); r[1] = (short)f2bf(lo.y);
  r[2] = (short)f2bf(lo.z); r[3] = (short)f2bf(lo.w);
  r[4] = (short)f2bf(hi.x); r[5] = (short)f2bf(hi.y);
  r[6] = (short)f2bf(hi.z); r[7] = (short)f2bf(hi.w);
  return r;
}

// ---------------------------------------------------------------------------
// K_degree: one streaming pass computing all degree vectors.
//   y=0: rowsum(adj_uu) -> dinv_uu = rsqrt(1+s)
//   y=1: rowsum(adj_cc) -> dinv_cc = rsqrt(1+s)
//   y=2: rowsum(adj_uc) -> du = rsqrt(s); colsums atomically into cs[8192]
// Block = 32 contiguous rows (1 MB sequential stream). Thread t owns cols
// {4t..4t+3} + 1024*m (m=0..7) -> column partials live in 32 registers;
// one scalar atomicAdd per owned column at block end (256 adds/address total).
// grid (256, 3) x 256  -> 3 blocks/CU, balanced, sequential DRAM streams.
// ---------------------------------------------------------------------------
__global__ __launch_bounds__(256) void k_degree(
    const float* __restrict__ a_uu, const float* __restrict__ a_cc,
    const float* __restrict__ a_uc,
    float* __restrict__ dinv_uu, float* __restrict__ dinv_cc,
    float* __restrict__ du, float* __restrict__ cs) {
  const int y = blockIdx.y;
  const float* A = (y == 0) ? a_uu : (y == 1) ? a_cc : a_uc;
  const bool uc = (y == 2);
  int t = threadIdx.x, w = t >> 6, l = t & 63;
  long r0 = (long)blockIdx.x * 32;
  __shared__ float rp_lds[32][4];

  float4 colacc[8];
#pragma unroll
  for (int m = 0; m < 8; ++m) colacc[m] = (float4){0.f, 0.f, 0.f, 0.f};

#pragma unroll 2
  for (int r = 0; r < 32; ++r) {
    const float* rowp = A + (r0 + r) * N_NODES + 4 * t;
    float4 v[8];
#pragma unroll
    for (int m = 0; m < 8; ++m) v[m] = *(const float4*)(rowp + 1024 * m);
    float rp = 0.f;
#pragma unroll
    for (int m = 0; m < 8; ++m) {
      rp += hsum4(v[m]);
      if (uc) acc4(colacc[m], v[m]);
    }
    rp = waveSum(rp);
    if (l == 0) rp_lds[r][w] = rp;
  }
  __syncthreads();
  if (t < 32) {
    float s = rp_lds[t][0] + rp_lds[t][1] + rp_lds[t][2] + rp_lds[t][3];
    if (y == 0) dinv_uu[r0 + t] = rsqrtf(1.0f + s);
    else if (y == 1) dinv_cc[r0 + t] = rsqrtf(1.0f + s);
    else du[r0 + t] = rsqrtf(s);
  }
  if (uc) {
#pragma unroll
    for (int m = 0; m < 8; ++m) {
      float* cp = cs + 4 * t + 1024 * m;
      atomicAdd(cp + 0, colacc[m].x);
      atomicAdd(cp + 1, colacc[m].y);
      atomicAdd(cp + 2, colacc[m].z);
      atomicAdd(cp + 3, colacc[m].w);
    }
  }
}

// ---------------------------------------------------------------------------
// K3: dc = rsqrt(colsum). grid 32 x 256 (cs fully accumulated by stream order)
// ---------------------------------------------------------------------------
__global__ __launch_bounds__(256) void k_finalize(const float* __restrict__ cs,
                                                  float* __restrict__ dc) {
  int i = blockIdx.x * 256 + threadIdx.x;
  dc[i] = rsqrtf(cs[i]);
}

// ---------------------------------------------------------------------------
// K0: P = proj_u @ weight_c (32x32). one block x 1024
// ---------------------------------------------------------------------------
__global__ void k_projw(const float* __restrict__ proj_u,
                        const float* __restrict__ weight_c, float* __restrict__ P) {
  int t = threadIdx.x;
  int i = t >> 5, j = t & 31;
  float s = 0.f;
#pragma unroll
  for (int k = 0; k < 32; ++k) s += proj_u[i * 32 + k] * weight_c[k * 32 + j];
  P[t] = s;
}

// ---------------------------------------------------------------------------
// K_sup: Bt[n][j] = bf16( dinv[j] * (X @ W)[j][n] ), transposed bf16 output
// y=0: X_U @ weight_s * dinv_uu ; y=1: X_C @ weight_s * dinv_cc ; y=2: X_U @ P * dc
// grid (1024, 3) x 256 (8 rows x 32 cols per block)
// ---------------------------------------------------------------------------
__global__ __launch_bounds__(256) void k_support(
    const float* __restrict__ X_U, const float* __restrict__ X_C,
    const float* __restrict__ weight_s, const float* __restrict__ P,
    const float* __restrict__ dinv_uu, const float* __restrict__ dinv_cc,
    const float* __restrict__ dc,
    unsigned short* __restrict__ bt_uu, unsigned short* __restrict__ bt_cc,
    unsigned short* __restrict__ bt_uc) {
  int m = blockIdx.y;
  const float* X = (m == 1) ? X_C : X_U;
  const float* W = (m == 2) ? P : weight_s;
  const float* dv = (m == 0) ? dinv_uu : (m == 1) ? dinv_cc : dc;
  unsigned short* bt = (m == 0) ? bt_uu : (m == 1) ? bt_cc : bt_uc;
  __shared__ float Wl[32][32];
  __shared__ float Xl[8][32];
  int t = threadIdx.x;
#pragma unroll
  for (int i = 0; i < 4; ++i) {
    int idx = t + 256 * i;
    Wl[idx >> 5][idx & 31] = W[idx];
  }
  int r = t >> 5, n = t & 31;
  int j0 = blockIdx.x * 8;
  Xl[r][n] = X[(long)(j0 + r) * 32 + n];
  __syncthreads();
  float s = 0.f;
#pragma unroll
  for (int k = 0; k < 32; ++k) s += Xl[r][k] * Wl[k][n];
  s *= dv[j0 + r];
  bt[(long)n * N_NODES + j0 + r] = f2bf(s);
}

// ---------------------------------------------------------------------------
// K5: out[i,n] = dsc[i] * sum_j adj[i,j]*Bt[n][j]   (M=K=8192, N=32)
// LDS-free, barrier-free: each wave owns a 16x16 output tile (mh=w&1, nh=w>>1)
// and loads its MFMA fragments straight from global. A (fp32) converted to
// bf16 in registers; B (bt) is 512 KB/matrix -> L2-resident. Register
// double-buffered 2-step pipeline keeps ~24 loads/lane in flight with no
// __syncthreads barrier drain and zero LDS bank conflicts.
// grid (256, 3) x 256  -> exactly 3 blocks/CU, balanced.
// ---------------------------------------------------------------------------
__global__ __launch_bounds__(256) void k_gemm(
    const float* __restrict__ adj_uu, const float* __restrict__ adj_cc,
    const float* __restrict__ adj_uc,
    const unsigned short* __restrict__ bt_uu, const unsigned short* __restrict__ bt_cc,
    const unsigned short* __restrict__ bt_uc,
    const float* __restrict__ dinv_uu, const float* __restrict__ dinv_cc,
    const float* __restrict__ du,
    float* __restrict__ out_u, float* __restrict__ c1, float* __restrict__ c2) {
  int m = blockIdx.y;
  const float* adj = (m == 0) ? adj_uu : (m == 1) ? adj_cc : adj_uc;
  const unsigned short* bt = (m == 0) ? bt_uu : (m == 1) ? bt_cc : bt_uc;
  const float* dsc = (m == 0) ? dinv_uu : (m == 1) ? dinv_cc : du;
  float* outp = (m == 0) ? out_u : (m == 1) ? c1 : c2;

  int t = threadIdx.x;
  int w = t >> 6, l = t & 63;
  int mh = w & 1, nh = w >> 1;
  long r0 = (long)blockIdx.x * 32;

  // Fragment element mapping identical to the harness-verified LDS version:
  // A[row = 16*mh + (l&15)][k = step*128 + kk*32 + (l>>4)*8 + j]  (fp32 -> bf16)
  // B[n   = 16*nh + (l&15)][k = step*128 + kk*32 + (l>>4)*8 + j]  (bf16)
  const float* pa = adj + (r0 + 16 * mh + (l & 15)) * (long)N_NODES + ((l >> 4) * 8);
  const short* pb = (const short*)bt + (long)(16 * nh + (l & 15)) * N_NODES + ((l >> 4) * 8);

  floatx4 acc = {0.f, 0.f, 0.f, 0.f};

  float4 a0[8]; short8 b0[4];
  float4 a1[8]; short8 b1[4];

#define LOAD_TILE(A_, B_, OFF)                                        \
  _Pragma("unroll") for (int kk = 0; kk < 4; ++kk) {                  \
    A_[2 * kk]     = *(const float4*)(pa + (OFF) + kk * 32);          \
    A_[2 * kk + 1] = *(const float4*)(pa + (OFF) + kk * 32 + 4);      \
    B_[kk]         = *(const short8*)(pb + (OFF) + kk * 32);          \
  }

#define COMPUTE_TILE(A_, B_)                                          \
  _Pragma("unroll") for (int kk = 0; kk < 4; ++kk) {                  \
    short8 af = cvt8(A_[2 * kk], A_[2 * kk + 1]);                     \
    acc = __builtin_amdgcn_mfma_f32_16x16x32_bf16(af, B_[kk], acc, 0, 0, 0); \
  }

  LOAD_TILE(a0, b0, 0)
  for (int step = 0; step < 64; step += 2) {
    LOAD_TILE(a1, b1, (step + 1) * 128)
    COMPUTE_TILE(a0, b0)
    if (step + 2 < 64) {
      LOAD_TILE(a0, b0, (step + 2) * 128)
    }
    COMPUTE_TILE(a1, b1)
  }
#undef LOAD_TILE
#undef COMPUTE_TILE

  // C/D layout (verified m89): col = lane&15, row = (lane>>4)*4 + reg
  int mrow = (int)r0 + 16 * mh + ((l >> 4) << 2);
  int ncol = 16 * nh + (l & 15);
#pragma unroll
  for (int r = 0; r < 4; ++r) {
    float sc = dsc[mrow + r];
    outp[(long)(mrow + r) * 32 + ncol] = sc * acc[r];
  }
}

// ---------------------------------------------------------------------------
// K_epi: attention + combine. 8 rows x 32 lanes per block. grid 1024 x 256
// out sections: [1]=node_embed_c, [2]=Y_c, [3]=Y_u
// ---------------------------------------------------------------------------
__global__ __launch_bounds__(256) void k_epilogue(
    const float* __restrict__ c1, const float* __restrict__ c2,
    const float* __restrict__ X_C, const float* __restrict__ W_lin,
    const float* __restrict__ a_vec, float* __restrict__ out) {
  __shared__ float Wl[64][32];
  __shared__ float al[32];
  int t = threadIdx.x;
#pragma unroll
  for (int i = 0; i < 8; ++i) {
    int idx = t + 256 * i;
    Wl[idx >> 5][idx & 31] = W_lin[idx];
  }
  if (t < 32) al[t] = a_vec[t];
  int g = t >> 5, n = t & 31;
  long row = (long)blockIdx.x * 8 + g;
  __syncthreads();
  float h1 = c1[row * 32 + n];
  float h2 = c2[row * 32 + n];
  float xv = X_C[row * 32 + n];
  float s1 = 0.f, s2 = 0.f, sx = 0.f;
#pragma unroll
  for (int k = 0; k < 32; ++k) {
    float h1k = __shfl(h1, k, 32);
    float h2k = __shfl(h2, k, 32);
    float xk = __shfl(xv, k, 32);
    float w0 = Wl[k][n], w1 = Wl[32 + k][n];
    s1 += h1k * w0;
    s2 += h2k * w0;
    sx += xk * w1;
  }
  float t1 = fmaxf(s1 + sx, 0.f) * al[n];
  float t2 = fmaxf(s2 + sx, 0.f) * al[n];
#pragma unroll
  for (int off = 16; off >= 1; off >>= 1) {
    t1 += __shfl_xor(t1, off, 32);
    t2 += __shfl_xor(t2, off, 32);
  }
  float mx = fmaxf(t1, t2);
  float e1 = expf(t1 - mx), e2 = expf(t2 - mx);
  float inv = 1.0f / (e1 + e2);
  float w1w = e1 * inv, w2w = e2 * inv;
  float yc = w1w * h1, yu = w2w * h2;
  long o = row * 32 + n;
  out[262144 + o] = yc + yu;  // node_embed_c
  out[524288 + o] = yc;       // Y_c
  out[786432 + o] = yu;       // Y_u
}

extern "C" void kernel_launch(void* const* d_in, const int* in_sizes, int n_in,
                              void* d_out, int out_size, void* d_ws, size_t ws_size,
                              hipStream_t stream) {
  (void)in_sizes; (void)n_in; (void)out_size; (void)ws_size;
  const float* X_U = (const float*)d_in[0];
  const float* X_C = (const float*)d_in[1];
  const float* adj_uu = (const float*)d_in[2];
  const float* adj_uc = (const float*)d_in[3];
  const float* adj_cc = (const float*)d_in[4];
  const float* weight_s = (const float*)d_in[5];
  const float* proj_u = (const float*)d_in[6];
  // d_in[7] = proj_c, unused in forward math
  const float* weight_c = (const float*)d_in[8];
  const float* W_lin = (const float*)d_in[9];
  const float* a_vec = (const float*)d_in[10];
  float* out = (float*)d_out;

  char* ws = (char*)d_ws;
  auto alloc = [&](size_t bytes) {
    char* p = ws;
    ws += (bytes + 255) & ~(size_t)255;
    return p;
  };
  float* dinv_uu = (float*)alloc(8192 * 4);
  float* dinv_cc = (float*)alloc(8192 * 4);
  float* du = (float*)alloc(8192 * 4);
  float* dc = (float*)alloc(8192 * 4);
  float* cs = (float*)alloc(8192 * 4);
  float* P = (float*)alloc(1024 * 4);
  float* c1 = (float*)alloc((size_t)262144 * 4);
  float* c2 = (float*)alloc((size_t)262144 * 4);
  unsigned short* bt_uu = (unsigned short*)alloc((size_t)262144 * 2);
  unsigned short* bt_cc = (unsigned short*)alloc((size_t)262144 * 2);
  unsigned short* bt_uc = (unsigned short*)alloc((size_t)262144 * 2);

  hipMemsetAsync(cs, 0, 8192 * 4, stream);
  hipLaunchKernelGGL(k_degree, dim3(256, 3), dim3(256), 0, stream,
                     adj_uu, adj_cc, adj_uc, dinv_uu, dinv_cc, du, cs);
  hipLaunchKernelGGL(k_finalize, dim3(32), dim3(256), 0, stream, cs, dc);
  hipLaunchKernelGGL(k_projw, dim3(1), dim3(1024), 0, stream, proj_u, weight_c, P);
  hipLaunchKernelGGL(k_support, dim3(1024, 3), dim3(256), 0, stream,
                     X_U, X_C, weight_s, P, dinv_uu, dinv_cc, dc, bt_uu, bt_cc, bt_uc);
  hipLaunchKernelGGL(k_gemm, dim3(256, 3), dim3(256), 0, stream,
                     adj_uu, adj_cc, adj_uc, bt_uu, bt_cc, bt_uc,
                     dinv_uu, dinv_cc, du, out, c1, c2);
  hipLaunchKernelGGL(k_epilogue, dim3(1024), dim3(256), 0, stream,
                     c1, c2, X_C, W_lin, a_vec, out);
}